// Round 8
// baseline (328.100 us; speedup 1.0000x reference)
//
#include <hip/hip_runtime.h>
#include <hip/hip_bf16.h>
#include <math.h>

#define N_NODES   100000
#define N_EDGES   3200000
#define NODE_DIM  128
#define HID       16
#define N_GRAPHS  256

// Bucketing: 128 nodes per bucket, block-major run layout.
#define BSHIFT    7
#define NPB       128                               // nodes per bucket
#define NBUCK     ((N_NODES + NPB - 1) >> BSHIFT)   // 782
#define NBLK      512                               // blocks in count/scatter
#define TOT       (NBUCK * NBLK)                    // 400384 count entries
#define ACCS      17                                // padded acc stride

// Fixed-point scales (float atomicAdd = CAS loop; int atomicAdd = native).
#define FIXA  1048576.0f        // 2^20 edge-accumulator scale
#define IFIXA (1.0f/1048576.0f)
#define FIXP  131072.0f         // 2^17 pool scale
#define IFIXP (1.0f/131072.0f)

__device__ __forceinline__ float bl(unsigned u) {
    union { unsigned i; float f; } x; x.i = u << 16; return x.f;
}
__device__ __forceinline__ float bh(unsigned u) {
    union { unsigned i; float f; } x; x.i = u & 0xffff0000u; return x.f;
}
__device__ __forceinline__ int fx(float v, float s) { return __float2int_rn(v * s); }

// ---------------------------------------------------------------------------
// Pass A: per-block bucket histogram. M[b*NBUCK + k] (block-major).
// ---------------------------------------------------------------------------
__global__ __launch_bounds__(256) void bucket_count(
    const int* __restrict__ dst, int* __restrict__ M, int E, int chunk)
{
    __shared__ int cnt[NBUCK];
    const int t = threadIdx.x, b = blockIdx.x;
    for (int k = t; k < NBUCK; k += 256) cnt[k] = 0;
    __syncthreads();
    int e0 = b * chunk, e1 = min(E, e0 + chunk);
    if (e1 > e0) {
        if (((e0 | e1) & 3) == 0) {
            const int4* d4 = (const int4*)dst;
            for (int i = (e0 >> 2) + t; i < (e1 >> 2); i += 256) {
                int4 d = d4[i];
                atomicAdd(&cnt[d.x >> BSHIFT], 1);
                atomicAdd(&cnt[d.y >> BSHIFT], 1);
                atomicAdd(&cnt[d.z >> BSHIFT], 1);
                atomicAdd(&cnt[d.w >> BSHIFT], 1);
            }
        } else {
            for (int e = e0 + t; e < e1; e += 256) atomicAdd(&cnt[dst[e] >> BSHIFT], 1);
        }
    }
    __syncthreads();
    for (int k = t; k < NBUCK; k += 256) M[b * NBUCK + k] = cnt[k];
}

// ---------------------------------------------------------------------------
// Hierarchical exclusive scan of M[0..TOT), 2048 elems per block.
// ---------------------------------------------------------------------------
__global__ __launch_bounds__(256) void scan_blocksum(
    const int* __restrict__ M, int* __restrict__ bsum, int n)
{
    __shared__ int red[256];
    int t = threadIdx.x;
    int base = blockIdx.x * 2048 + t * 8;
    int s = 0;
    #pragma unroll
    for (int k = 0; k < 8; ++k) { int i = base + k; if (i < n) s += M[i]; }
    red[t] = s; __syncthreads();
    for (int o = 128; o > 0; o >>= 1) {
        if (t < o) red[t] += red[t + o];
        __syncthreads();
    }
    if (t == 0) bsum[blockIdx.x] = red[0];
}

__global__ __launch_bounds__(256) void scan_bsums(int* __restrict__ bsum, int nb)
{
    __shared__ int tmp[256];
    int t = threadIdx.x;
    int v = (t < nb) ? bsum[t] : 0;
    tmp[t] = v; __syncthreads();
    for (int o = 1; o < 256; o <<= 1) {
        int a = (t >= o) ? tmp[t - o] : 0;
        __syncthreads();
        tmp[t] += a;
        __syncthreads();
    }
    if (t < nb) bsum[t] = tmp[t] - v;   // exclusive
}

__global__ __launch_bounds__(256) void scan_write(
    int* __restrict__ M, const int* __restrict__ bsum, int n, int Etot)
{
    __shared__ int tsum[256];
    int t = threadIdx.x;
    int base = blockIdx.x * 2048 + t * 8;
    int v[8]; int s = 0;
    #pragma unroll
    for (int k = 0; k < 8; ++k) { int i = base + k; v[k] = (i < n) ? M[i] : 0; s += v[k]; }
    tsum[t] = s; __syncthreads();
    int mine = s;
    for (int o = 1; o < 256; o <<= 1) {
        int a = (t >= o) ? tsum[t - o] : 0;
        __syncthreads();
        tsum[t] += a;
        __syncthreads();
    }
    int pre = bsum[blockIdx.x] + tsum[t] - mine;
    #pragma unroll
    for (int k = 0; k < 8; ++k) {
        int i = base + k;
        if (i < n) { M[i] = pre; pre += v[k]; }
    }
    if (blockIdx.x == 0 && t == 0) M[n] = Etot;   // sentinel
}

// ---------------------------------------------------------------------------
// Pass C: bin edges. Block b writes only its private contiguous window
// [M[b*NBUCK], M[(b+1)*NBUCK]) — lines complete in one XCD's L2.
// Payload: src | (dloc << 17).
// ---------------------------------------------------------------------------
__global__ __launch_bounds__(256) void bucket_scatter(
    const int* __restrict__ src, const int* __restrict__ dst,
    const int* __restrict__ gOff, int* __restrict__ ebuf, int E, int chunk)
{
    __shared__ int cur[NBUCK];
    const int t = threadIdx.x, b = blockIdx.x;
    for (int k = t; k < NBUCK; k += 256) cur[k] = gOff[b * NBUCK + k];
    __syncthreads();
    int e0 = b * chunk, e1 = min(E, e0 + chunk);
    if (e1 <= e0) return;
    if (((e0 | e1) & 3) == 0) {
        const int4* d4 = (const int4*)dst;
        const int4* s4 = (const int4*)src;
        for (int i = (e0 >> 2) + t; i < (e1 >> 2); i += 256) {
            int4 d = d4[i];
            int4 s = s4[i];
            int p;
            p = atomicAdd(&cur[d.x >> BSHIFT], 1); ebuf[p] = s.x | ((d.x & (NPB-1)) << 17);
            p = atomicAdd(&cur[d.y >> BSHIFT], 1); ebuf[p] = s.y | ((d.y & (NPB-1)) << 17);
            p = atomicAdd(&cur[d.z >> BSHIFT], 1); ebuf[p] = s.z | ((d.z & (NPB-1)) << 17);
            p = atomicAdd(&cur[d.w >> BSHIFT], 1); ebuf[p] = s.w | ((d.w & (NPB-1)) << 17);
        }
    } else {
        for (int e = e0 + t; e < e1; e += 256) {
            int d = dst[e];
            int p = atomicAdd(&cur[d >> BSHIFT], 1);
            ebuf[p] = src[e] | ((d & (NPB-1)) << 17);
        }
    }
}

// ---------------------------------------------------------------------------
// Per-bucket degree histogram -> dinv. Bucket k's edges live in NBLK runs:
// run b = [M[b*NBUCK+k], M[b*NBUCK+k+1])  (sentinel makes this uniform).
// ---------------------------------------------------------------------------
__global__ __launch_bounds__(256) void deg_dinv(
    const int* __restrict__ M, const int* __restrict__ ebuf,
    float* __restrict__ dinv, int N)
{
    __shared__ int hist[NPB];
    const int k = blockIdx.x, t = threadIdx.x;
    if (t < NPB) hist[t] = 0;
    __syncthreads();
    for (int b = t; b < NBLK; b += 256) {
        int s = M[b * NBUCK + k];
        int e = M[b * NBUCK + k + 1];
        for (int j = s; j < e; ++j) atomicAdd(&hist[ebuf[j] >> 17], 1);
    }
    __syncthreads();
    int n = (k << BSHIFT) + t;
    if (t < NPB && n < N) dinv[n] = rsqrtf((float)(hist[t] + 1));
}

// ---------------------------------------------------------------------------
// xws_bf16[n][k] = bf16(dinv[n] * (x[n] @ W)[k])  — 32 B/node, 3.2 MB total.
// ---------------------------------------------------------------------------
__global__ __launch_bounds__(256) void xw_kernel(
    const float* __restrict__ x, const float* __restrict__ W,
    const float* __restrict__ dinv, unsigned short* __restrict__ xws, int N)
{
    __shared__ float sW[NODE_DIM * HID];   // 8 KB
    __shared__ float sx[64 * 129];         // ~33 KB
    const int t = threadIdx.x;

    #pragma unroll
    for (int i = 0; i < 8; ++i) sW[i * 256 + t] = W[i * 256 + t];

    const int base = blockIdx.x * 64;
    #pragma unroll
    for (int i = 0; i < 8; ++i) {
        int idx  = i * 256 + t;
        int row  = idx >> 5;
        int col4 = idx & 31;
        float4 v = make_float4(0.f, 0.f, 0.f, 0.f);
        int n = base + row;
        if (n < N) v = ((const float4*)x)[(size_t)n * 32 + col4];
        float* d = &sx[row * 129 + col4 * 4];
        d[0] = v.x; d[1] = v.y; d[2] = v.z; d[3] = v.w;
    }
    __syncthreads();

    #pragma unroll
    for (int o = 0; o < 4; ++o) {
        int out_idx = o * 256 + t;
        int row = out_idx >> 4, dim = out_idx & 15;
        const float* xr = &sx[row * 129];
        float acc = 0.f;
        #pragma unroll 4
        for (int k = 0; k < NODE_DIM; ++k) acc += xr[k] * sW[k * HID + dim];
        int n = base + row;
        if (n < N) {
            __hip_bfloat16 b = __float2bfloat16(acc * dinv[n]);
            xws[(size_t)n * HID + dim] = *(unsigned short*)&b;
        }
    }
}

// ---------------------------------------------------------------------------
// Per-bucket gather + self-loop + ReLU + mean-pool. Runs walked 4-wide per
// 2-lane subgroup for MLP; fixed-point int LDS accumulation (native ds_add).
// ---------------------------------------------------------------------------
__global__ __launch_bounds__(256, 4) void gather_pool(
    const int* __restrict__ M, const int* __restrict__ ebuf,
    const float* __restrict__ dinv, const unsigned short* __restrict__ xws,
    const float* __restrict__ gcn_b, const int* __restrict__ batch,
    int* __restrict__ pool, int* __restrict__ cnt, int N)
{
    __shared__ int acc[NPB * ACCS];      // 8.5 KB fixed-point
    __shared__ int rs[NBLK];             // 2 KB run starts
    __shared__ int re[NBLK];             // 2 KB run ends
    __shared__ int lpool[16 * HID];      // 1 KB
    __shared__ int lcnt[16];
    const int k = blockIdx.x, t = threadIdx.x;
    const int base = k << BSHIFT;

    for (int i = t; i < NPB * ACCS; i += 256) acc[i] = 0;
    if (t < 16 * HID) lpool[t] = 0;
    if (t < 16) lcnt[t] = 0;
    for (int b = t; b < NBLK; b += 256) {
        rs[b] = M[b * NBUCK + k];
        re[b] = M[b * NBUCK + k + 1];
    }
    __syncthreads();

    const int sub = t >> 1, h = t & 1;   // 128 subgroups of 2 lanes
    const uint4* xw4 = (const uint4*)xws;

    int i0 = rs[sub],       n0 = re[sub];
    int i1 = rs[sub + 128], n1 = re[sub + 128];
    int i2 = rs[sub + 256], n2 = re[sub + 256];
    int i3 = rs[sub + 384], n3 = re[sub + 384];

    // steady: 4 independent runs -> 4 gathers in flight
    while (i0 < n0 && i1 < n1 && i2 < n2 && i3 < n3) {
        int w0 = ebuf[i0++];
        int w1 = ebuf[i1++];
        int w2 = ebuf[i2++];
        int w3 = ebuf[i3++];
        uint4 v0 = xw4[(size_t)(w0 & 0x1FFFF) * 2 + h];
        uint4 v1 = xw4[(size_t)(w1 & 0x1FFFF) * 2 + h];
        uint4 v2 = xw4[(size_t)(w2 & 0x1FFFF) * 2 + h];
        uint4 v3 = xw4[(size_t)(w3 & 0x1FFFF) * 2 + h];
        int* p;
        p = &acc[(w0 >> 17) * ACCS + h * 8];
        atomicAdd(p+0, fx(bl(v0.x),FIXA)); atomicAdd(p+1, fx(bh(v0.x),FIXA));
        atomicAdd(p+2, fx(bl(v0.y),FIXA)); atomicAdd(p+3, fx(bh(v0.y),FIXA));
        atomicAdd(p+4, fx(bl(v0.z),FIXA)); atomicAdd(p+5, fx(bh(v0.z),FIXA));
        atomicAdd(p+6, fx(bl(v0.w),FIXA)); atomicAdd(p+7, fx(bh(v0.w),FIXA));
        p = &acc[(w1 >> 17) * ACCS + h * 8];
        atomicAdd(p+0, fx(bl(v1.x),FIXA)); atomicAdd(p+1, fx(bh(v1.x),FIXA));
        atomicAdd(p+2, fx(bl(v1.y),FIXA)); atomicAdd(p+3, fx(bh(v1.y),FIXA));
        atomicAdd(p+4, fx(bl(v1.z),FIXA)); atomicAdd(p+5, fx(bh(v1.z),FIXA));
        atomicAdd(p+6, fx(bl(v1.w),FIXA)); atomicAdd(p+7, fx(bh(v1.w),FIXA));
        p = &acc[(w2 >> 17) * ACCS + h * 8];
        atomicAdd(p+0, fx(bl(v2.x),FIXA)); atomicAdd(p+1, fx(bh(v2.x),FIXA));
        atomicAdd(p+2, fx(bl(v2.y),FIXA)); atomicAdd(p+3, fx(bh(v2.y),FIXA));
        atomicAdd(p+4, fx(bl(v2.z),FIXA)); atomicAdd(p+5, fx(bh(v2.z),FIXA));
        atomicAdd(p+6, fx(bl(v2.w),FIXA)); atomicAdd(p+7, fx(bh(v2.w),FIXA));
        p = &acc[(w3 >> 17) * ACCS + h * 8];
        atomicAdd(p+0, fx(bl(v3.x),FIXA)); atomicAdd(p+1, fx(bh(v3.x),FIXA));
        atomicAdd(p+2, fx(bl(v3.y),FIXA)); atomicAdd(p+3, fx(bh(v3.y),FIXA));
        atomicAdd(p+4, fx(bl(v3.z),FIXA)); atomicAdd(p+5, fx(bh(v3.z),FIXA));
        atomicAdd(p+6, fx(bl(v3.w),FIXA)); atomicAdd(p+7, fx(bh(v3.w),FIXA));
    }
    // drain each run
    #pragma unroll
    for (int r = 0; r < 4; ++r) {
        int i = (r == 0) ? i0 : (r == 1) ? i1 : (r == 2) ? i2 : i3;
        int n = (r == 0) ? n0 : (r == 1) ? n1 : (r == 2) ? n2 : n3;
        for (; i < n; ++i) {
            int w = ebuf[i];
            uint4 v = xw4[(size_t)(w & 0x1FFFF) * 2 + h];
            int* p = &acc[(w >> 17) * ACCS + h * 8];
            atomicAdd(p+0, fx(bl(v.x),FIXA)); atomicAdd(p+1, fx(bh(v.x),FIXA));
            atomicAdd(p+2, fx(bl(v.y),FIXA)); atomicAdd(p+3, fx(bh(v.y),FIXA));
            atomicAdd(p+4, fx(bl(v.z),FIXA)); atomicAdd(p+5, fx(bh(v.z),FIXA));
            atomicAdd(p+6, fx(bl(v.w),FIXA)); atomicAdd(p+7, fx(bh(v.w),FIXA));
        }
    }
    __syncthreads();

    // epilogue: self-loop + bias + relu + pool (16-lane groups per node)
    int nN = min(NPB, N - base);
    int gmin = batch[base], gmax = batch[base + nN - 1];
    int range = gmax - gmin + 1;
    bool useL = (range <= 16);
    const int sub16 = t >> 4, lane = t & 15;
    float bb = gcn_b[lane];

    for (int i = sub16; i < nN; i += 16) {
        int n = base + i;
        union { unsigned u; float f; } sv;
        sv.u = ((unsigned)xws[(size_t)n * HID + lane]) << 16;
        float a = (float)acc[i * ACCS + lane] * IFIXA + sv.f;
        float r = fmaxf(fmaf(dinv[n], a, bb), 0.f);
        int g = batch[n];
        int ri = fx(r, FIXP);
        if (useL) {
            atomicAdd(&lpool[(g - gmin) * HID + lane], ri);
            if (lane == 0) atomicAdd(&lcnt[g - gmin], 1);
        } else {
            atomicAdd(&pool[g * HID + lane], ri);
            if (lane == 0) atomicAdd(&cnt[g], 1);
        }
    }
    __syncthreads();

    if (useL) {
        for (int i = t; i < range * HID; i += 256) {
            int v = lpool[i];
            if (v != 0) atomicAdd(&pool[gmin * HID + i], v);
        }
        for (int i = t; i < range; i += 256) {
            int c = lcnt[i];
            if (c != 0) atomicAdd(&cnt[gmin + i], c);
        }
    }
}

// ---------------------------------------------------------------------------
// Per-graph head: one wave per graph.
// ---------------------------------------------------------------------------
__global__ __launch_bounds__(64) void head_kernel(
    const int* __restrict__ pool, const int* __restrict__ cnt,
    const float* __restrict__ mri,  const float* __restrict__ cog,
    const float* __restrict__ clin, const float* __restrict__ gen,
    const float* __restrict__ mriW, const float* __restrict__ mrib,
    const float* __restrict__ cogW, const float* __restrict__ cogb,
    const float* __restrict__ clinW, const float* __restrict__ clinb,
    const float* __restrict__ genW, const float* __restrict__ genb,
    const float* __restrict__ W1, const float* __restrict__ b1,
    const float* __restrict__ W2, const float* __restrict__ b2,
    float* __restrict__ out)
{
    const int g = blockIdx.x;
    const int lane = threadIdx.x;
    __shared__ float comb[32];
    __shared__ float h[HID];

    if (lane < HID) {
        float c = fmaxf((float)cnt[g], 1.f);
        comb[lane] = ((float)pool[g * HID + lane] * IFIXP) / c;
    }

    struct Mod { const float* in; const float* W; const float* b; int K; int off; };
    Mod mods[4] = {
        { mri  + (size_t)g * 256, mriW,  mrib,  256, 16 },
        { cog  + (size_t)g * 64,  cogW,  cogb,  64,  20 },
        { clin + (size_t)g * 32,  clinW, clinb, 32,  24 },
        { gen  + (size_t)g * 512, genW,  genb,  512, 28 },
    };
    for (int m = 0; m < 4; ++m) {
        float p0 = 0.f, p1 = 0.f, p2 = 0.f, p3 = 0.f;
        const float* in = mods[m].in;
        const float* Wm = mods[m].W;
        for (int kk = lane; kk < mods[m].K; kk += 64) {
            float xv = in[kk];
            p0 += xv * Wm[kk * 4 + 0];
            p1 += xv * Wm[kk * 4 + 1];
            p2 += xv * Wm[kk * 4 + 2];
            p3 += xv * Wm[kk * 4 + 3];
        }
        #pragma unroll
        for (int o = 32; o > 0; o >>= 1) {
            p0 += __shfl_down(p0, o);
            p1 += __shfl_down(p1, o);
            p2 += __shfl_down(p2, o);
            p3 += __shfl_down(p3, o);
        }
        if (lane == 0) {
            const float* bm = mods[m].b;
            int o = mods[m].off;
            comb[o + 0] = fmaxf(p0 + bm[0], 0.f);
            comb[o + 1] = fmaxf(p1 + bm[1], 0.f);
            comb[o + 2] = fmaxf(p2 + bm[2], 0.f);
            comb[o + 3] = fmaxf(p3 + bm[3], 0.f);
        }
    }
    __syncthreads();

    if (lane < HID) {
        float a = b1[lane];
        #pragma unroll
        for (int kk = 0; kk < 32; ++kk) a += comb[kk] * W1[kk * HID + lane];
        h[lane] = fmaxf(a, 0.f);
    }
    __syncthreads();

    if (lane == 0) {
        float l0 = b2[0], l1 = b2[1], l2 = b2[2];
        #pragma unroll
        for (int kk = 0; kk < HID; ++kk) {
            float hv = h[kk];
            l0 += hv * W2[kk * 3 + 0];
            l1 += hv * W2[kk * 3 + 1];
            l2 += hv * W2[kk * 3 + 2];
        }
        float mx = fmaxf(l0, fmaxf(l1, l2));
        float lse = mx + logf(expf(l0 - mx) + expf(l1 - mx) + expf(l2 - mx));
        out[g * 3 + 0] = l0 - lse;
        out[g * 3 + 1] = l1 - lse;
        out[g * 3 + 2] = l2 - lse;
    }
}

// ---------------------------------------------------------------------------
// Launch
// ---------------------------------------------------------------------------
extern "C" void kernel_launch(void* const* d_in, const int* in_sizes, int n_in,
                              void* d_out, int out_size, void* d_ws, size_t ws_size,
                              hipStream_t stream)
{
    const float* x     = (const float*)d_in[0];
    const int*   eidx  = (const int*)d_in[1];
    const int*   batch = (const int*)d_in[2];
    const float* mri   = (const float*)d_in[3];
    const float* cog   = (const float*)d_in[4];
    const float* clin  = (const float*)d_in[5];
    const float* gen   = (const float*)d_in[6];
    const float* gcn_W = (const float*)d_in[7];
    const float* gcn_b = (const float*)d_in[8];
    const float* mriW  = (const float*)d_in[9];
    const float* mrib  = (const float*)d_in[10];
    const float* cogW  = (const float*)d_in[11];
    const float* cogb  = (const float*)d_in[12];
    const float* clinW = (const float*)d_in[13];
    const float* clinb = (const float*)d_in[14];
    const float* genW  = (const float*)d_in[15];
    const float* genb  = (const float*)d_in[16];
    const float* W1    = (const float*)d_in[17];
    const float* b1    = (const float*)d_in[18];
    const float* W2    = (const float*)d_in[19];
    const float* b2    = (const float*)d_in[20];
    float* out = (float*)d_out;

    const int N = in_sizes[0] / NODE_DIM;   // 100000
    const int E = in_sizes[1] / 2;          // 3200000
    const int* src = eidx;
    const int* dst = eidx + E;

    // workspace layout (4-byte units)
    float* ws   = (float*)d_ws;
    unsigned short* xws = (unsigned short*)ws;   // 1.6M ushort = 400,000 slots
    float* dinv = ws + 800000;               //   100,000 f
    int*   pool = (int*)(ws + 900000);       //     4,096 i (fixed-point)
    int*   cnt  = (int*)(ws + 904096);       //       256 i
    int*   M    = (int*)(ws + 905000);       //   400,385 i (incl sentinel)
    int*   bsum = (int*)(ws + 1305500);      //       256 i
    int*   ebuf = (int*)(ws + 1306000);      // 3,200,000 i

    const int chunkE = (((E + NBLK - 1) / NBLK) + 3) & ~3;   // 6252, 4-aligned
    const int scanNB = (TOT + 2047) / 2048;                  // 196

    hipMemsetAsync(pool, 0, (N_GRAPHS * HID + N_GRAPHS) * sizeof(int), stream);

    bucket_count<<<NBLK, 256, 0, stream>>>(dst, M, E, chunkE);
    scan_blocksum<<<scanNB, 256, 0, stream>>>(M, bsum, TOT);
    scan_bsums<<<1, 256, 0, stream>>>(bsum, scanNB);
    scan_write<<<scanNB, 256, 0, stream>>>(M, bsum, TOT, E);
    bucket_scatter<<<NBLK, 256, 0, stream>>>(src, dst, M, ebuf, E, chunkE);
    deg_dinv<<<NBUCK, 256, 0, stream>>>(M, ebuf, dinv, N);
    xw_kernel<<<(N + 63) / 64, 256, 0, stream>>>(x, gcn_W, dinv, xws, N);
    gather_pool<<<NBUCK, 256, 0, stream>>>(M, ebuf, dinv, xws, gcn_b, batch,
                                           pool, cnt, N);
    head_kernel<<<N_GRAPHS, 64, 0, stream>>>(
        pool, cnt, mri, cog, clin, gen,
        mriW, mrib, cogW, cogb, clinW, clinb, genW, genb,
        W1, b1, W2, b2, out);
}

// Round 9
// 260.690 us; speedup vs baseline: 1.2586x; 1.2586x over previous
//
#include <hip/hip_runtime.h>
#include <hip/hip_bf16.h>
#include <math.h>

#define N_NODES   100000
#define N_EDGES   3200000
#define NODE_DIM  128
#define HID       16
#define N_GRAPHS  256

// Bucketing: 64 nodes per bucket, bucket-major runs (coalesced gather).
#define BSHIFT    6
#define NPB       64                                // nodes per bucket
#define NBUCK     ((N_NODES + NPB - 1) >> BSHIFT)   // 1563
#define NBLK      256                               // blocks in count/scatter
#define TOT       (NBUCK * NBLK)                    // 400128 count entries
#define ACCS      17                                // padded acc stride

// Fixed-point scales (float atomicAdd = CAS loop; int atomicAdd = native).
#define FIXA  1048576.0f        // 2^20 edge-accumulator scale
#define IFIXA (1.0f/1048576.0f)
#define FIXP  131072.0f         // 2^17 pool scale
#define IFIXP (1.0f/131072.0f)

__device__ __forceinline__ float bl(unsigned u) {
    union { unsigned i; float f; } x; x.i = u << 16; return x.f;
}
__device__ __forceinline__ float bh(unsigned u) {
    union { unsigned i; float f; } x; x.i = u & 0xffff0000u; return x.f;
}
__device__ __forceinline__ int fx(float v, float s) { return __float2int_rn(v * s); }

// ---------------------------------------------------------------------------
// Pass A: per-block bucket histogram. 1024 threads (16 waves/CU) for MLP.
// ---------------------------------------------------------------------------
__global__ __launch_bounds__(1024) void bucket_count(
    const int* __restrict__ dst, int* __restrict__ M, int E, int chunk)
{
    __shared__ int cnt[NBUCK];
    const int t = threadIdx.x, b = blockIdx.x;
    for (int k = t; k < NBUCK; k += 1024) cnt[k] = 0;
    __syncthreads();
    int e0 = b * chunk, e1 = min(E, e0 + chunk);
    if (e1 > e0) {
        if (((e0 | e1) & 3) == 0) {
            const int4* d4 = (const int4*)dst;
            for (int i = (e0 >> 2) + t; i < (e1 >> 2); i += 1024) {
                int4 d = d4[i];
                atomicAdd(&cnt[d.x >> BSHIFT], 1);
                atomicAdd(&cnt[d.y >> BSHIFT], 1);
                atomicAdd(&cnt[d.z >> BSHIFT], 1);
                atomicAdd(&cnt[d.w >> BSHIFT], 1);
            }
        } else {
            for (int e = e0 + t; e < e1; e += 1024) atomicAdd(&cnt[dst[e] >> BSHIFT], 1);
        }
    }
    __syncthreads();
    for (int k = t; k < NBUCK; k += 1024) M[k * NBLK + b] = cnt[k];
}

// ---------------------------------------------------------------------------
// Hierarchical exclusive scan of M[0..TOT), 2048 elems per block.
// ---------------------------------------------------------------------------
__global__ __launch_bounds__(256) void scan_blocksum(
    const int* __restrict__ M, int* __restrict__ bsum, int n)
{
    __shared__ int red[256];
    int t = threadIdx.x;
    int base = blockIdx.x * 2048 + t * 8;
    int s = 0;
    #pragma unroll
    for (int k = 0; k < 8; ++k) { int i = base + k; if (i < n) s += M[i]; }
    red[t] = s; __syncthreads();
    for (int o = 128; o > 0; o >>= 1) {
        if (t < o) red[t] += red[t + o];
        __syncthreads();
    }
    if (t == 0) bsum[blockIdx.x] = red[0];
}

__global__ __launch_bounds__(256) void scan_bsums(int* __restrict__ bsum, int nb)
{
    __shared__ int tmp[256];
    int t = threadIdx.x;
    int v = (t < nb) ? bsum[t] : 0;
    tmp[t] = v; __syncthreads();
    for (int o = 1; o < 256; o <<= 1) {
        int a = (t >= o) ? tmp[t - o] : 0;
        __syncthreads();
        tmp[t] += a;
        __syncthreads();
    }
    if (t < nb) bsum[t] = tmp[t] - v;   // exclusive
}

__global__ __launch_bounds__(256) void scan_write(
    int* __restrict__ M, const int* __restrict__ bsum, int n)
{
    __shared__ int tsum[256];
    int t = threadIdx.x;
    int base = blockIdx.x * 2048 + t * 8;
    int v[8]; int s = 0;
    #pragma unroll
    for (int k = 0; k < 8; ++k) { int i = base + k; v[k] = (i < n) ? M[i] : 0; s += v[k]; }
    tsum[t] = s; __syncthreads();
    int mine = s;
    for (int o = 1; o < 256; o <<= 1) {
        int a = (t >= o) ? tsum[t - o] : 0;
        __syncthreads();
        tsum[t] += a;
        __syncthreads();
    }
    int pre = bsum[blockIdx.x] + tsum[t] - mine;
    #pragma unroll
    for (int k = 0; k < 8; ++k) {
        int i = base + k;
        if (i < n) { M[i] = pre; pre += v[k]; }
    }
}

// ---------------------------------------------------------------------------
// Pass C: bin edges by dst bucket. 1024 threads. Payload: src | (dloc<<17).
// ---------------------------------------------------------------------------
__global__ __launch_bounds__(1024) void bucket_scatter(
    const int* __restrict__ src, const int* __restrict__ dst,
    const int* __restrict__ gOff, int* __restrict__ ebuf, int E, int chunk)
{
    __shared__ int cur[NBUCK];
    const int t = threadIdx.x, b = blockIdx.x;
    for (int k = t; k < NBUCK; k += 1024) cur[k] = gOff[k * NBLK + b];
    __syncthreads();
    int e0 = b * chunk, e1 = min(E, e0 + chunk);
    if (e1 <= e0) return;
    if (((e0 | e1) & 3) == 0) {
        const int4* d4 = (const int4*)dst;
        const int4* s4 = (const int4*)src;
        for (int i = (e0 >> 2) + t; i < (e1 >> 2); i += 1024) {
            int4 d = d4[i];
            int4 s = s4[i];
            int p;
            p = atomicAdd(&cur[d.x >> BSHIFT], 1); ebuf[p] = s.x | ((d.x & (NPB-1)) << 17);
            p = atomicAdd(&cur[d.y >> BSHIFT], 1); ebuf[p] = s.y | ((d.y & (NPB-1)) << 17);
            p = atomicAdd(&cur[d.z >> BSHIFT], 1); ebuf[p] = s.z | ((d.z & (NPB-1)) << 17);
            p = atomicAdd(&cur[d.w >> BSHIFT], 1); ebuf[p] = s.w | ((d.w & (NPB-1)) << 17);
        }
    } else {
        for (int e = e0 + t; e < e1; e += 1024) {
            int d = dst[e];
            int p = atomicAdd(&cur[d >> BSHIFT], 1);
            ebuf[p] = src[e] | ((d & (NPB-1)) << 17);
        }
    }
}

// ---------------------------------------------------------------------------
// Per-bucket degree histogram -> dinv (contiguous bucket region).
// ---------------------------------------------------------------------------
__global__ __launch_bounds__(256) void deg_dinv(
    const int* __restrict__ gOff, const int* __restrict__ ebuf,
    float* __restrict__ dinv, int E, int N)
{
    __shared__ int hist[NPB];
    const int k = blockIdx.x, t = threadIdx.x;
    if (t < NPB) hist[t] = 0;
    __syncthreads();
    int e0 = gOff[k * NBLK];
    int e1 = (k + 1 < NBUCK) ? gOff[(k + 1) * NBLK] : E;
    for (int e = e0 + t; e < e1; e += 256) atomicAdd(&hist[ebuf[e] >> 17], 1);
    __syncthreads();
    int n = (k << BSHIFT) + t;
    if (t < NPB && n < N) dinv[n] = rsqrtf((float)(hist[t] + 1));
}

// ---------------------------------------------------------------------------
// xws_bf16[n][k] = bf16(dinv[n] * (x[n] @ W)[k])  — 32 B/node, 3.2 MB total.
// ---------------------------------------------------------------------------
__global__ __launch_bounds__(256) void xw_kernel(
    const float* __restrict__ x, const float* __restrict__ W,
    const float* __restrict__ dinv, unsigned short* __restrict__ xws, int N)
{
    __shared__ float sW[NODE_DIM * HID];   // 8 KB
    __shared__ float sx[64 * 129];         // ~33 KB
    const int t = threadIdx.x;

    #pragma unroll
    for (int i = 0; i < 8; ++i) sW[i * 256 + t] = W[i * 256 + t];

    const int base = blockIdx.x * 64;
    #pragma unroll
    for (int i = 0; i < 8; ++i) {
        int idx  = i * 256 + t;
        int row  = idx >> 5;
        int col4 = idx & 31;
        float4 v = make_float4(0.f, 0.f, 0.f, 0.f);
        int n = base + row;
        if (n < N) v = ((const float4*)x)[(size_t)n * 32 + col4];
        float* d = &sx[row * 129 + col4 * 4];
        d[0] = v.x; d[1] = v.y; d[2] = v.z; d[3] = v.w;
    }
    __syncthreads();

    #pragma unroll
    for (int o = 0; o < 4; ++o) {
        int out_idx = o * 256 + t;
        int row = out_idx >> 4, dim = out_idx & 15;
        const float* xr = &sx[row * 129];
        float acc = 0.f;
        #pragma unroll 4
        for (int k = 0; k < NODE_DIM; ++k) acc += xr[k] * sW[k * HID + dim];
        int n = base + row;
        if (n < N) {
            __hip_bfloat16 b = __float2bfloat16(acc * dinv[n]);
            xws[(size_t)n * HID + dim] = *(unsigned short*)&b;
        }
    }
}

// ---------------------------------------------------------------------------
// Per-bucket gather + self-loop + ReLU + mean-pool (round-7 structure:
// contiguous region, 2-lane/edge coalesced, unroll x8, fixed-point LDS).
// ---------------------------------------------------------------------------
__global__ __launch_bounds__(256, 4) void gather_pool(
    const int* __restrict__ gOff, const int* __restrict__ ebuf,
    const float* __restrict__ dinv, const unsigned short* __restrict__ xws,
    const float* __restrict__ gcn_b, const int* __restrict__ batch,
    int* __restrict__ pool, int* __restrict__ cnt, int E, int N)
{
    __shared__ int acc[NPB * ACCS];      // 4.25 KB fixed-point
    __shared__ int lpool[16 * HID];      // 1 KB fixed-point
    __shared__ int lcnt[16];
    const int k = blockIdx.x, t = threadIdx.x;
    const int base = k << BSHIFT;

    for (int i = t; i < NPB * ACCS; i += 256) acc[i] = 0;
    if (t < 16 * HID) lpool[t] = 0;
    if (t < 16) lcnt[t] = 0;
    __syncthreads();

    int e0 = gOff[k * NBLK];
    int e1 = (k + 1 < NBUCK) ? gOff[(k + 1) * NBLK] : E;
    const int sub = t >> 1, h = t & 1;   // 128 edge-subgroups of 2 lanes
    const uint4* xw4 = (const uint4*)xws;

    int e = e0 + sub;
    for (; e + 7 * 128 < e1; e += 8 * 128) {
        int w0 = ebuf[e];
        int w1 = ebuf[e + 128];
        int w2 = ebuf[e + 256];
        int w3 = ebuf[e + 384];
        int w4 = ebuf[e + 512];
        int w5 = ebuf[e + 640];
        int w6 = ebuf[e + 768];
        int w7 = ebuf[e + 896];
        uint4 v0 = xw4[(size_t)(w0 & 0x1FFFF) * 2 + h];
        uint4 v1 = xw4[(size_t)(w1 & 0x1FFFF) * 2 + h];
        uint4 v2 = xw4[(size_t)(w2 & 0x1FFFF) * 2 + h];
        uint4 v3 = xw4[(size_t)(w3 & 0x1FFFF) * 2 + h];
        uint4 v4 = xw4[(size_t)(w4 & 0x1FFFF) * 2 + h];
        uint4 v5 = xw4[(size_t)(w5 & 0x1FFFF) * 2 + h];
        uint4 v6 = xw4[(size_t)(w6 & 0x1FFFF) * 2 + h];
        uint4 v7 = xw4[(size_t)(w7 & 0x1FFFF) * 2 + h];
        int* p;
        p = &acc[(w0 >> 17) * ACCS + h * 8];
        atomicAdd(p+0, fx(bl(v0.x),FIXA)); atomicAdd(p+1, fx(bh(v0.x),FIXA));
        atomicAdd(p+2, fx(bl(v0.y),FIXA)); atomicAdd(p+3, fx(bh(v0.y),FIXA));
        atomicAdd(p+4, fx(bl(v0.z),FIXA)); atomicAdd(p+5, fx(bh(v0.z),FIXA));
        atomicAdd(p+6, fx(bl(v0.w),FIXA)); atomicAdd(p+7, fx(bh(v0.w),FIXA));
        p = &acc[(w1 >> 17) * ACCS + h * 8];
        atomicAdd(p+0, fx(bl(v1.x),FIXA)); atomicAdd(p+1, fx(bh(v1.x),FIXA));
        atomicAdd(p+2, fx(bl(v1.y),FIXA)); atomicAdd(p+3, fx(bh(v1.y),FIXA));
        atomicAdd(p+4, fx(bl(v1.z),FIXA)); atomicAdd(p+5, fx(bh(v1.z),FIXA));
        atomicAdd(p+6, fx(bl(v1.w),FIXA)); atomicAdd(p+7, fx(bh(v1.w),FIXA));
        p = &acc[(w2 >> 17) * ACCS + h * 8];
        atomicAdd(p+0, fx(bl(v2.x),FIXA)); atomicAdd(p+1, fx(bh(v2.x),FIXA));
        atomicAdd(p+2, fx(bl(v2.y),FIXA)); atomicAdd(p+3, fx(bh(v2.y),FIXA));
        atomicAdd(p+4, fx(bl(v2.z),FIXA)); atomicAdd(p+5, fx(bh(v2.z),FIXA));
        atomicAdd(p+6, fx(bl(v2.w),FIXA)); atomicAdd(p+7, fx(bh(v2.w),FIXA));
        p = &acc[(w3 >> 17) * ACCS + h * 8];
        atomicAdd(p+0, fx(bl(v3.x),FIXA)); atomicAdd(p+1, fx(bh(v3.x),FIXA));
        atomicAdd(p+2, fx(bl(v3.y),FIXA)); atomicAdd(p+3, fx(bh(v3.y),FIXA));
        atomicAdd(p+4, fx(bl(v3.z),FIXA)); atomicAdd(p+5, fx(bh(v3.z),FIXA));
        atomicAdd(p+6, fx(bl(v3.w),FIXA)); atomicAdd(p+7, fx(bh(v3.w),FIXA));
        p = &acc[(w4 >> 17) * ACCS + h * 8];
        atomicAdd(p+0, fx(bl(v4.x),FIXA)); atomicAdd(p+1, fx(bh(v4.x),FIXA));
        atomicAdd(p+2, fx(bl(v4.y),FIXA)); atomicAdd(p+3, fx(bh(v4.y),FIXA));
        atomicAdd(p+4, fx(bl(v4.z),FIXA)); atomicAdd(p+5, fx(bh(v4.z),FIXA));
        atomicAdd(p+6, fx(bl(v4.w),FIXA)); atomicAdd(p+7, fx(bh(v4.w),FIXA));
        p = &acc[(w5 >> 17) * ACCS + h * 8];
        atomicAdd(p+0, fx(bl(v5.x),FIXA)); atomicAdd(p+1, fx(bh(v5.x),FIXA));
        atomicAdd(p+2, fx(bl(v5.y),FIXA)); atomicAdd(p+3, fx(bh(v5.y),FIXA));
        atomicAdd(p+4, fx(bl(v5.z),FIXA)); atomicAdd(p+5, fx(bh(v5.z),FIXA));
        atomicAdd(p+6, fx(bl(v5.w),FIXA)); atomicAdd(p+7, fx(bh(v5.w),FIXA));
        p = &acc[(w6 >> 17) * ACCS + h * 8];
        atomicAdd(p+0, fx(bl(v6.x),FIXA)); atomicAdd(p+1, fx(bh(v6.x),FIXA));
        atomicAdd(p+2, fx(bl(v6.y),FIXA)); atomicAdd(p+3, fx(bh(v6.y),FIXA));
        atomicAdd(p+4, fx(bl(v6.z),FIXA)); atomicAdd(p+5, fx(bh(v6.z),FIXA));
        atomicAdd(p+6, fx(bl(v6.w),FIXA)); atomicAdd(p+7, fx(bh(v6.w),FIXA));
        p = &acc[(w7 >> 17) * ACCS + h * 8];
        atomicAdd(p+0, fx(bl(v7.x),FIXA)); atomicAdd(p+1, fx(bh(v7.x),FIXA));
        atomicAdd(p+2, fx(bl(v7.y),FIXA)); atomicAdd(p+3, fx(bh(v7.y),FIXA));
        atomicAdd(p+4, fx(bl(v7.z),FIXA)); atomicAdd(p+5, fx(bh(v7.z),FIXA));
        atomicAdd(p+6, fx(bl(v7.w),FIXA)); atomicAdd(p+7, fx(bh(v7.w),FIXA));
    }
    for (; e < e1; e += 128) {
        int w = ebuf[e];
        uint4 v = xw4[(size_t)(w & 0x1FFFF) * 2 + h];
        int* p = &acc[(w >> 17) * ACCS + h * 8];
        atomicAdd(p+0, fx(bl(v.x),FIXA)); atomicAdd(p+1, fx(bh(v.x),FIXA));
        atomicAdd(p+2, fx(bl(v.y),FIXA)); atomicAdd(p+3, fx(bh(v.y),FIXA));
        atomicAdd(p+4, fx(bl(v.z),FIXA)); atomicAdd(p+5, fx(bh(v.z),FIXA));
        atomicAdd(p+6, fx(bl(v.w),FIXA)); atomicAdd(p+7, fx(bh(v.w),FIXA));
    }
    __syncthreads();

    // epilogue: self-loop + bias + relu + pool (16-lane groups per node)
    int nN = min(NPB, N - base);
    int gmin = batch[base], gmax = batch[base + nN - 1];
    int range = gmax - gmin + 1;
    bool useL = (range <= 16);
    const int sub16 = t >> 4, lane = t & 15;
    float bb = gcn_b[lane];

    for (int i = sub16; i < nN; i += 16) {
        int n = base + i;
        union { unsigned u; float f; } sv;
        sv.u = ((unsigned)xws[(size_t)n * HID + lane]) << 16;
        float a = (float)acc[i * ACCS + lane] * IFIXA + sv.f;
        float r = fmaxf(fmaf(dinv[n], a, bb), 0.f);
        int g = batch[n];
        int ri = fx(r, FIXP);
        if (useL) {
            atomicAdd(&lpool[(g - gmin) * HID + lane], ri);
            if (lane == 0) atomicAdd(&lcnt[g - gmin], 1);
        } else {
            atomicAdd(&pool[g * HID + lane], ri);
            if (lane == 0) atomicAdd(&cnt[g], 1);
        }
    }
    __syncthreads();

    if (useL) {
        for (int i = t; i < range * HID; i += 256) {
            int v = lpool[i];
            if (v != 0) atomicAdd(&pool[gmin * HID + i], v);
        }
        for (int i = t; i < range; i += 256) {
            int c = lcnt[i];
            if (c != 0) atomicAdd(&cnt[gmin + i], c);
        }
    }
}

// ---------------------------------------------------------------------------
// Per-graph head: one wave per graph.
// ---------------------------------------------------------------------------
__global__ __launch_bounds__(64) void head_kernel(
    const int* __restrict__ pool, const int* __restrict__ cnt,
    const float* __restrict__ mri,  const float* __restrict__ cog,
    const float* __restrict__ clin, const float* __restrict__ gen,
    const float* __restrict__ mriW, const float* __restrict__ mrib,
    const float* __restrict__ cogW, const float* __restrict__ cogb,
    const float* __restrict__ clinW, const float* __restrict__ clinb,
    const float* __restrict__ genW, const float* __restrict__ genb,
    const float* __restrict__ W1, const float* __restrict__ b1,
    const float* __restrict__ W2, const float* __restrict__ b2,
    float* __restrict__ out)
{
    const int g = blockIdx.x;
    const int lane = threadIdx.x;
    __shared__ float comb[32];
    __shared__ float h[HID];

    if (lane < HID) {
        float c = fmaxf((float)cnt[g], 1.f);
        comb[lane] = ((float)pool[g * HID + lane] * IFIXP) / c;
    }

    struct Mod { const float* in; const float* W; const float* b; int K; int off; };
    Mod mods[4] = {
        { mri  + (size_t)g * 256, mriW,  mrib,  256, 16 },
        { cog  + (size_t)g * 64,  cogW,  cogb,  64,  20 },
        { clin + (size_t)g * 32,  clinW, clinb, 32,  24 },
        { gen  + (size_t)g * 512, genW,  genb,  512, 28 },
    };
    for (int m = 0; m < 4; ++m) {
        float p0 = 0.f, p1 = 0.f, p2 = 0.f, p3 = 0.f;
        const float* in = mods[m].in;
        const float* Wm = mods[m].W;
        for (int kk = lane; kk < mods[m].K; kk += 64) {
            float xv = in[kk];
            p0 += xv * Wm[kk * 4 + 0];
            p1 += xv * Wm[kk * 4 + 1];
            p2 += xv * Wm[kk * 4 + 2];
            p3 += xv * Wm[kk * 4 + 3];
        }
        #pragma unroll
        for (int o = 32; o > 0; o >>= 1) {
            p0 += __shfl_down(p0, o);
            p1 += __shfl_down(p1, o);
            p2 += __shfl_down(p2, o);
            p3 += __shfl_down(p3, o);
        }
        if (lane == 0) {
            const float* bm = mods[m].b;
            int o = mods[m].off;
            comb[o + 0] = fmaxf(p0 + bm[0], 0.f);
            comb[o + 1] = fmaxf(p1 + bm[1], 0.f);
            comb[o + 2] = fmaxf(p2 + bm[2], 0.f);
            comb[o + 3] = fmaxf(p3 + bm[3], 0.f);
        }
    }
    __syncthreads();

    if (lane < HID) {
        float a = b1[lane];
        #pragma unroll
        for (int kk = 0; kk < 32; ++kk) a += comb[kk] * W1[kk * HID + lane];
        h[lane] = fmaxf(a, 0.f);
    }
    __syncthreads();

    if (lane == 0) {
        float l0 = b2[0], l1 = b2[1], l2 = b2[2];
        #pragma unroll
        for (int kk = 0; kk < HID; ++kk) {
            float hv = h[kk];
            l0 += hv * W2[kk * 3 + 0];
            l1 += hv * W2[kk * 3 + 1];
            l2 += hv * W2[kk * 3 + 2];
        }
        float mx = fmaxf(l0, fmaxf(l1, l2));
        float lse = mx + logf(expf(l0 - mx) + expf(l1 - mx) + expf(l2 - mx));
        out[g * 3 + 0] = l0 - lse;
        out[g * 3 + 1] = l1 - lse;
        out[g * 3 + 2] = l2 - lse;
    }
}

// ---------------------------------------------------------------------------
// Launch
// ---------------------------------------------------------------------------
extern "C" void kernel_launch(void* const* d_in, const int* in_sizes, int n_in,
                              void* d_out, int out_size, void* d_ws, size_t ws_size,
                              hipStream_t stream)
{
    const float* x     = (const float*)d_in[0];
    const int*   eidx  = (const int*)d_in[1];
    const int*   batch = (const int*)d_in[2];
    const float* mri   = (const float*)d_in[3];
    const float* cog   = (const float*)d_in[4];
    const float* clin  = (const float*)d_in[5];
    const float* gen   = (const float*)d_in[6];
    const float* gcn_W = (const float*)d_in[7];
    const float* gcn_b = (const float*)d_in[8];
    const float* mriW  = (const float*)d_in[9];
    const float* mrib  = (const float*)d_in[10];
    const float* cogW  = (const float*)d_in[11];
    const float* cogb  = (const float*)d_in[12];
    const float* clinW = (const float*)d_in[13];
    const float* clinb = (const float*)d_in[14];
    const float* genW  = (const float*)d_in[15];
    const float* genb  = (const float*)d_in[16];
    const float* W1    = (const float*)d_in[17];
    const float* b1    = (const float*)d_in[18];
    const float* W2    = (const float*)d_in[19];
    const float* b2    = (const float*)d_in[20];
    float* out = (float*)d_out;

    const int N = in_sizes[0] / NODE_DIM;   // 100000
    const int E = in_sizes[1] / 2;          // 3200000
    const int* src = eidx;
    const int* dst = eidx + E;

    // workspace layout (4-byte units)
    float* ws   = (float*)d_ws;
    unsigned short* xws = (unsigned short*)ws;   // 1.6M ushort
    float* dinv = ws + 800000;               //   100,000 f
    int*   pool = (int*)(ws + 900000);       //     4,096 i (fixed-point)
    int*   cnt  = (int*)(ws + 904096);       //       256 i
    int*   M    = (int*)(ws + 905000);       //   400,128 i
    int*   bsum = (int*)(ws + 1305200);      //       256 i
    int*   ebuf = (int*)(ws + 1306000);      // 3,200,000 i

    const int chunkE = (E + NBLK - 1) / NBLK;       // 12500 (4-aligned)
    const int scanNB = (TOT + 2047) / 2048;         // 196

    hipMemsetAsync(pool, 0, (N_GRAPHS * HID + N_GRAPHS) * sizeof(int), stream);

    bucket_count<<<NBLK, 1024, 0, stream>>>(dst, M, E, chunkE);
    scan_blocksum<<<scanNB, 256, 0, stream>>>(M, bsum, TOT);
    scan_bsums<<<1, 256, 0, stream>>>(bsum, scanNB);
    scan_write<<<scanNB, 256, 0, stream>>>(M, bsum, TOT);
    bucket_scatter<<<NBLK, 1024, 0, stream>>>(src, dst, M, ebuf, E, chunkE);
    deg_dinv<<<NBUCK, 256, 0, stream>>>(M, ebuf, dinv, E, N);
    xw_kernel<<<(N + 63) / 64, 256, 0, stream>>>(x, gcn_W, dinv, xws, N);
    gather_pool<<<NBUCK, 256, 0, stream>>>(M, ebuf, dinv, xws, gcn_b, batch,
                                           pool, cnt, E, N);
    head_kernel<<<N_GRAPHS, 64, 0, stream>>>(
        pool, cnt, mri, cog, clin, gen,
        mriW, mrib, cogW, cogb, clinW, clinb, genW, genb,
        W1, b1, W2, b2, out);
}